// Round 6
// baseline (121.100 us; speedup 1.0000x reference)
//
#include <hip/hip_runtime.h>

// BoundaryLoss, fully fused: per (b,k,which) plane-mask, exact separable
// squared EDT entirely in LDS + fused x*dist contraction -> one f64 atomic
// per block -> last block writes mean. Single kernel launch.
//
// x (8,4,256,256) f32; y (8,1,256,256) i32 in [0,4). out: scalar f32.
// dist_map: +d(pos) at neg pixels, (1-d(neg)) at pos pixels, 0 if class absent.
// All squared distances are exact integers (<=130050): sqrtf + f32 mul + f64
// accumulation reproduces the np reference to ~1e-10 (absmax 0.0 measured).

#define HH 256
#define WW 256
#define NPIX (HH*WW)
#define NPM 64              // 8 b * 4 k * 2 which
#define BIG (1 << 27)
#define SEGS 4
#define RSEG 64             // rows per thread-segment

__global__ __launch_bounds__(1024, 1) void boundary_fused(
        const int* __restrict__ y, const float* __restrict__ x,
        double* __restrict__ acc, unsigned int* __restrict__ cnt,
        float* __restrict__ out)
{
    __shared__ unsigned short d[HH][WW];   // 128 KB: whole plane-mask
    __shared__ short segLast[SEGS][WW];    // last feature row in segment (-1000 none)
    __shared__ short segFirst[SEGS][WW];   // first feature row in segment (1000 none)
    __shared__ double wsum[16];
    __shared__ int lastFlag;

    int pm    = blockIdx.x;      // 0..63
    int which = pm & 1;          // 0: feature=(y==k), 1: feature=(y!=k)
    int plane = pm >> 1;
    int b     = plane >> 2;
    int k     = plane & 3;

    int t   = threadIdx.x;
    int w   = t & (WW - 1);      // column
    int seg = t >> 8;            // 0..3
    int h0  = seg * RSEG;

    const int*   yp = y + b * NPIX;
    const float* xp = x + (size_t)plane * NPIX;

    // ---- vertical forward (downward) local scan: LDS only ----
    int lastL = -1000, firstL = 1000;
    for (int i = 0; i < RSEG; ++i) {
        int h    = h0 + i;
        int lab  = yp[h * WW + w];                 // 1KB/row coalesced
        int feat = ((lab == k) ? 1 : 0) ^ which;
        if (feat) { lastL = h; if (firstL > 900) firstL = h; }
        d[h][w] = (unsigned short)min(h - lastL, 1000);
    }
    segLast[seg][w]  = (short)lastL;
    segFirst[seg][w] = (short)firstL;
    __syncthreads();

    // ---- cross-segment prefix: nearest feature above / below my segment ----
    int prevLast = -1000;
    for (int s = seg - 1; s >= 0; --s) {
        int v = segLast[s][w];
        if (v >= 0) { prevLast = v; break; }
    }
    int nextFirst = 1000;
    for (int s = seg + 1; s < SEGS; ++s) {
        int v = segFirst[s][w];
        if (v < 900) { nextFirst = v; break; }
    }

    // ---- vertical backward: combine, square, store back to LDS ----
    int nd = nextFirst;                            // nearest feature row >= h
    for (int i = RSEG - 1; i >= 0; --i) {
        int h  = h0 + i;
        int du = d[h][w];
        if (du == 0) nd = h;                       // feature pixel
        int dup = min(du, h - prevLast);
        int ddn = nd - h;
        int m   = min(min(dup, ddn), 256);
        d[h][w] = (m > 255) ? (unsigned short)0xFFFF
                            : (unsigned short)(m * m);   // <= 65025
    }
    __syncthreads();

    // ---- horizontal batched-pruned exact search + fused contraction ----
    // min_j d[h][j] + (w-j)^2; radii in batches of 4 (8 LDS loads overlapped),
    // prune once per batch (lossless: candidates at |w-j|>=bs are >= bs^2).
    // Boundary clamp to col 0/255 is exact: clamped candidate >= an already-
    // examined true candidate (see R2 derivation).
    double lsum = 0.0;
    for (int i = 0; i < RSEG; ++i) {
        int h  = h0 + i;
        int gc = d[h][w];
        int best = (gc == 0xFFFF) ? BIG : gc;
        #pragma unroll 1
        for (int bs = 1; bs < WW; bs += 4) {
            if (bs * bs >= best) break;
            int m = best;
            #pragma unroll
            for (int u = 0; u < 4; ++u) {
                int r  = bs + u;
                int rr = r * r;
                int jl = max(w - r, 0);
                int jr = min(w + r, WW - 1);
                int gl = d[h][jl]; gl = (gl == 0xFFFF) ? BIG : gl;
                int gr = d[h][jr]; gr = (gr == 0xFFFF) ? BIG : gr;
                m = min(m, gl + rr);
                m = min(m, gr + rr);
            }
            best = m;
        }
        // best==0: feature pixel (term 0). best>=BIG: class absent (has_pos).
        if (best > 0 && best < BIG) {
            float xv   = xp[h * WW + w];
            float dd   = sqrtf((float)best);           // exact-int sqrt
            float term = which ? (1.0f - dd) : dd;     // == -(d-1) exactly
            lsum += (double)(xv * term);
        }
    }

    // ---- block reduction: wave butterfly then 16 wave leaders ----
    for (int off = 32; off > 0; off >>= 1)
        lsum += __shfl_down(lsum, off, 64);
    int lane = t & 63, wv = t >> 6;
    if (lane == 0) wsum[wv] = lsum;
    __syncthreads();

    if (t == 0) {
        double s = 0.0;
        #pragma unroll
        for (int i = 0; i < 16; ++i) s += wsum[i];
        atomicAdd(acc, s);                       // device-scope f64 add
        __threadfence();                         // release before ticket
        unsigned int ticket = atomicAdd(cnt, 1u);
        lastFlag = (ticket == NPM - 1) ? 1 : 0;
    }
    __syncthreads();

    // ---- last block finalizes: read total, write mean ----
    if (lastFlag && t == 0) {
        __threadfence();                         // acquire
        double total = atomicAdd(acc, 0.0);      // coherent read
        out[0] = (float)(total * (1.0 / 2097152.0));
    }
}

extern "C" void kernel_launch(void* const* d_in, const int* in_sizes, int n_in,
                              void* d_out, int out_size, void* d_ws, size_t ws_size,
                              hipStream_t stream) {
    const float* x = (const float*)d_in[0];
    const int*   y = (const int*)d_in[1];
    float* out = (float*)d_out;

    // ws layout: [0,8) f64 accumulator, [8,12) u32 ticket counter
    double*       acc = (double*)d_ws;
    unsigned int* cnt = (unsigned int*)((char*)d_ws + 8);

    hipMemsetAsync(d_ws, 0, 16, stream);         // zero acc+cnt (capturable)
    boundary_fused<<<NPM, 1024, 0, stream>>>(y, x, acc, cnt, out);
}

// Round 7
// 108.498 us; speedup vs baseline: 1.1161x; 1.1161x over previous
//
#include <hip/hip_runtime.h>

// BoundaryLoss: exact separable squared EDT per (b,k,which) plane-mask,
// fused with x*dist contraction. Two launches, all 256 CUs busy.
//
// x (8,4,256,256) f32; y (8,1,256,256) i32 in [0,4). out: scalar f32.
// dist_map: +d(pos) at neg px, (1-d(neg)) at pos px, 0 if class absent.
// All squared distances are exact integers (<=130050): sqrtf + f32 mul + f64
// accumulation reproduces the np reference to ~1e-10 (absmax 0.0 measured).
//
// R6 lesson: whole-plane-in-LDS fusion = 64 blocks = 64/256 CUs = 65us.
// Latency-bound work scales with px/CU -> spread thin, max waves/CU.

#define HH 256
#define WW 256
#define NPIX (HH*WW)
#define NPM 64              // 8 b * 4 k * 2 which
#define BIG (1 << 27)

// accumulator stripes (64 * 64B apart) + ticket counter live after g in ws
#define NSTRIPE 64

// ---------------- Kernel 1: vertical pass (segmented column scan) ----------
// grid: 64 pm * 16 col-chunks = 1024 blocks, 256 threads -> 4 blk/CU, 16 w/CU.
// thread = (segment 0..15) x (local col 0..15); each scans 16 rows of 1 col.
#define SEGS 16
#define RSEG 16
#define CPB 16

__global__ __launch_bounds__(256, 4) void edt_vpass(
        const int* __restrict__ y, unsigned short* __restrict__ g,
        double* __restrict__ acc, unsigned int* __restrict__ cnt) {
    __shared__ unsigned short d[HH][CPB + 1];   // pad -> conflict-free
    __shared__ short segLast[SEGS][CPB];        // last feature row (-1000 none)
    __shared__ short segFirst[SEGS][CPB];       // first feature row (1000 none)

    int bid   = blockIdx.x;
    int pm    = bid >> 4;               // 0..63
    int cc    = bid & 15;               // col chunk
    int which = pm & 1;                 // 0: feature=(y==k), 1: feature=(y!=k)
    int plane = pm >> 1;
    int b     = plane >> 2;
    int k     = plane & 3;

    int t   = threadIdx.x;
    int col = t & (CPB - 1);
    int seg = t >> 4;
    int w   = cc * CPB + col;
    int h0  = seg * RSEG;

    // block 0 zeroes the stripe accumulators + ticket (runs before hpass)
    if (bid == 0) {
        if (t < NSTRIPE * 8) acc[t] = 0.0;
        if (t == 0) *cnt = 0u;
    }

    const int* yp = y + b * NPIX;
    unsigned short* gp = g + (size_t)pm * NPIX;

    // forward (downward) local scan
    int lastL = -1000, firstL = 1000;
    for (int i = 0; i < RSEG; ++i) {
        int h   = h0 + i;
        int lab = yp[h * WW + w];
        int feat = ((lab == k) ? 1 : 0) ^ which;
        if (feat) { lastL = h; if (firstL > 900) firstL = h; }
        d[h][col] = (unsigned short)min(h - lastL, 1000);
    }
    segLast[seg][col]  = (short)lastL;
    segFirst[seg][col] = (short)firstL;
    __syncthreads();

    // cross-segment prefix: nearest feature above / below my segment
    int prevLast = -1000;
    for (int s = seg - 1; s >= 0; --s) {
        int v = segLast[s][col];
        if (v >= 0) { prevLast = v; break; }
    }
    int nextFirst = 1000;
    for (int s = seg + 1; s < SEGS; ++s) {
        int v = segFirst[s][col];
        if (v < 900) { nextFirst = v; break; }
    }

    // backward scan + combine + square + store to global g
    int nd = nextFirst;
    for (int i = RSEG - 1; i >= 0; --i) {
        int h  = h0 + i;
        int du = d[h][col];
        if (du == 0) nd = h;
        int dup = min(du, h - prevLast);
        int ddn = nd - h;
        int m   = min(min(dup, ddn), 256);
        gp[h * WW + w] = (m > 255) ? (unsigned short)0xFFFF
                                   : (unsigned short)(m * m);   // <= 65025
    }
}

// ---------------- Kernel 2: horizontal pass + contraction + finalize -------
// grid: 64 pm * 32 row-chunks = 2048 blocks, 256 threads (thread = column w)
// -> 8 blk/CU, 32 waves/CU (8KB tile). Batched pruned exact search:
// min_j g[j]+(w-j)^2, radii 4 at a time (8 LDS loads overlapped), prune per
// batch (lossless). Boundary clamp exact (see derivation in R2 notes).
#define ROWS_PER_BLK 8
#define NBLK2 2048

__global__ __launch_bounds__(256, 8) void edt_hpass(
        const unsigned short* __restrict__ g, const float* __restrict__ x,
        double* __restrict__ acc, unsigned int* __restrict__ cnt,
        float* __restrict__ out) {
    __shared__ int tile[ROWS_PER_BLK][WW];   // sentinel pre-mapped to BIG
    __shared__ double wsum[4];
    __shared__ int lastFlag;

    int bid   = blockIdx.x;
    int pm    = bid >> 5;
    int rc    = bid & 31;
    int r0    = rc * ROWS_PER_BLK;
    int which = pm & 1;
    int plane = pm >> 1;
    int t     = threadIdx.x;   // = w

    const unsigned short* gp = g + (size_t)pm * NPIX;
    const float* xp = x + (size_t)plane * NPIX;

    // tile fill: uint loads (2 px); 8 rows * 128 uints = 1024 = 4*256
    const unsigned int* gp32 = (const unsigned int*)(gp + r0 * WW);
    #pragma unroll
    for (int i2 = 0; i2 < 4; ++i2) {
        int idx = i2 * 256 + t;
        int row = idx >> 7;
        int c2  = idx & 127;
        unsigned int v = gp32[row * 128 + c2];
        int v0 = (int)(v & 0xFFFFu);
        int v1 = (int)(v >> 16);
        tile[row][2 * c2]     = (v0 == 0xFFFF) ? BIG : v0;
        tile[row][2 * c2 + 1] = (v1 == 0xFFFF) ? BIG : v1;
    }
    __syncthreads();

    double lsum = 0.0;
    for (int i = 0; i < ROWS_PER_BLK; ++i) {
        int best = tile[i][t];
        #pragma unroll 1
        for (int bs = 1; bs < WW; bs += 4) {
            if (bs * bs >= best) break;          // lossless prune
            int m = best;
            #pragma unroll
            for (int u = 0; u < 4; ++u) {
                int r  = bs + u;
                int rr = r * r;
                int jl = max(t - r, 0);
                int jr = min(t + r, WW - 1);
                m = min(m, tile[i][jl] + rr);
                m = min(m, tile[i][jr] + rr);
            }
            best = m;
        }
        // best==0: feature px (term 0). best>=BIG: class absent (has_pos).
        if (best > 0 && best < BIG) {
            float xv   = xp[(r0 + i) * WW + t];
            float dd   = sqrtf((float)best);           // exact-int sqrt
            float term = which ? (1.0f - dd) : dd;     // == -(d-1) exactly
            lsum += (double)(xv * term);
        }
    }

    // block reduction: wave butterfly then 4 wave leaders
    for (int off = 32; off > 0; off >>= 1)
        lsum += __shfl_down(lsum, off, 64);
    int lane = t & 63, wv = t >> 6;
    if (lane == 0) wsum[wv] = lsum;
    __syncthreads();

    if (t == 0) {
        double s = wsum[0] + wsum[1] + wsum[2] + wsum[3];
        atomicAdd(&acc[(bid & (NSTRIPE - 1)) * 8], s);  // striped, device-scope
        __threadfence();
        unsigned int ticket = atomicAdd(cnt, 1u);
        lastFlag = (ticket == NBLK2 - 1) ? 1 : 0;
    }
    __syncthreads();

    // last block reduces the 64 stripes (atomic reads: coherent) -> mean
    if (lastFlag && t < 64) {
        __threadfence();
        double v = atomicAdd(&acc[t * 8], 0.0);
        for (int off = 32; off > 0; off >>= 1)
            v += __shfl_down(v, off, 64);
        if (t == 0) out[0] = (float)(v * (1.0 / 2097152.0));
    }
}

extern "C" void kernel_launch(void* const* d_in, const int* in_sizes, int n_in,
                              void* d_out, int out_size, void* d_ws, size_t ws_size,
                              hipStream_t stream) {
    const float* x = (const float*)d_in[0];
    const int*   y = (const int*)d_in[1];
    float* out = (float*)d_out;

    // ws layout: [0, 8MB) u16 g planes; then 64 striped f64 accs (64B apart);
    // then u32 ticket counter.
    unsigned short* g   = (unsigned short*)d_ws;
    double*         acc = (double*)((char*)d_ws + (size_t)NPM * NPIX * sizeof(unsigned short));
    unsigned int*   cnt = (unsigned int*)((char*)acc + NSTRIPE * 8 * sizeof(double));

    edt_vpass<<<1024, 256, 0, stream>>>(y, g, acc, cnt);
    edt_hpass<<<NBLK2, 256, 0, stream>>>(g, x, acc, cnt, out);
}

// Round 9
// 83.969 us; speedup vs baseline: 1.4422x; 1.2921x over previous
//
#include <hip/hip_runtime.h>

// BoundaryLoss: exact separable squared EDT per (b,k,which) plane-mask,
// fused with x*dist contraction. R4-measured structure (78.9us total),
// finalize kernel folded into hpass via fence-free ordered atomics.
//
// x (8,4,256,256) f32; y (8,1,256,256) i32 in [0,4). out: scalar f32.
// dist_map: +d(pos) at neg px, (1-d(neg)) at pos px, 0 if class absent.
// All squared distances are exact integers (<=130050): sqrtf + f32 mul + f64
// accumulation reproduces the np reference to ~1e-10 (absmax 0.0 measured).
//
// Lessons: R6 whole-plane fusion (64 blocks) = 65us (latency-bound, 1/4 CUs).
// R7 __threadfence-per-block + __launch_bounds__(256,8) (VGPR=8!) = hpass 52us.
// Keep R4's exact launch configs; no launch_bounds; no threadfence.

#define HH 256
#define WW 256
#define NPIX (HH*WW)
#define NPM 64              // 8 b * 4 k * 2 which
#define BIG (1 << 27)
#define NSTRIPE 64          // f64 accumulator stripes, 64B apart

// ---------------- Kernel 1: vertical pass (segmented column scan) ----------
// grid: 64 pm * 8 col-chunks = 512 blocks, 256 threads (R4-measured config).
// thread = (segment 0..7) x (local col 0..31); each scans 32 rows of 1 column.
#define SEGS 8
#define RSEG 32
#define CPB 32

__global__ void edt_vpass(const int* __restrict__ y, unsigned short* __restrict__ g,
                          double* __restrict__ acc, unsigned int* __restrict__ cnt) {
    __shared__ unsigned short d[HH][CPB + 1];   // +1 pad
    __shared__ short segLast[SEGS][CPB];        // last feature row (-1000 none)
    __shared__ short segFirst[SEGS][CPB];       // first feature row (1000 none)

    int bid   = blockIdx.x;
    int pm    = bid >> 3;               // 0..63
    int cc    = bid & 7;                // col chunk
    int which = pm & 1;                 // 0: feature=(y==k), 1: feature=(y!=k)
    int plane = pm >> 1;
    int b     = plane >> 2;
    int k     = plane & 3;

    int t   = threadIdx.x;
    int col = t & (CPB - 1);
    int seg = t >> 5;
    int w   = cc * CPB + col;
    int h0  = seg * RSEG;

    // block 0 zeroes stripe accumulators + ticket (vpass completes before hpass)
    if (bid == 0) {
        acc[t] = 0.0; acc[t + 256] = 0.0;       // 512 doubles
        if (t == 0) *cnt = 0u;
    }

    const int* yp = y + b * NPIX;
    unsigned short* gp = g + (size_t)pm * NPIX;

    // forward (downward) local scan
    int lastL = -1000, firstL = 1000;
    for (int i = 0; i < RSEG; ++i) {
        int h   = h0 + i;
        int lab = yp[h * WW + w];
        int feat = ((lab == k) ? 1 : 0) ^ which;
        if (feat) { lastL = h; if (firstL > 900) firstL = h; }
        d[h][col] = (unsigned short)min(h - lastL, 1000);
    }
    segLast[seg][col]  = (short)lastL;
    segFirst[seg][col] = (short)firstL;
    __syncthreads();

    // cross-segment prefix: nearest feature above / below my segment
    int prevLast = -1000;
    for (int s = seg - 1; s >= 0; --s) {
        int v = segLast[s][col];
        if (v >= 0) { prevLast = v; break; }
    }
    int nextFirst = 1000;
    for (int s = seg + 1; s < SEGS; ++s) {
        int v = segFirst[s][col];
        if (v < 900) { nextFirst = v; break; }
    }

    // backward scan + combine + square + store
    int nd = nextFirst;
    for (int i = RSEG - 1; i >= 0; --i) {
        int h  = h0 + i;
        int du = d[h][col];
        if (du == 0) nd = h;
        int dup = min(du, h - prevLast);
        int ddn = nd - h;
        int m   = min(min(dup, ddn), 256);
        gp[h * WW + w] = (m > 255) ? (unsigned short)0xFFFF
                                   : (unsigned short)(m * m);   // <= 65025
    }
}

// ---------------- Kernel 2: horizontal pass + contraction + finalize -------
// grid: 64 pm * 16 row-chunks = 1024 blocks, 256 threads (R4-measured config).
// Batched pruned exact search: min_j g[j]+(w-j)^2, radii 4 at a time (8 LDS
// loads overlapped), prune per batch (lossless). Boundary clamp exact.
// Finalize: striped f64 atomics; s_waitcnt vmcnt(0) (per-wave, no cache op)
// orders stripe-add before ticket-add; last ticket reduces stripes.
#define ROWS_PER_BLK 16
#define NBLK2 1024

__global__ void edt_hpass(const unsigned short* __restrict__ g,
                          const float* __restrict__ x,
                          double* __restrict__ acc, unsigned int* __restrict__ cnt,
                          float* __restrict__ out) {
    __shared__ int tile[ROWS_PER_BLK][WW];   // sentinel pre-mapped to BIG
    __shared__ double wsum[4];
    __shared__ int lastFlag;

    int bid   = blockIdx.x;
    int pm    = bid >> 4;
    int rc    = bid & 15;
    int r0    = rc * ROWS_PER_BLK;
    int which = pm & 1;
    int plane = pm >> 1;
    int t     = threadIdx.x;   // = w

    const unsigned short* gp = g + (size_t)pm * NPIX;
    const float* xp = x + (size_t)plane * NPIX;

    // tile fill: uint loads (2 px); 16 rows * 128 uints = 2048 = 8*256
    // (lane-consecutive cols -> conflict-free ds_write, coalesced global)
    const unsigned int* gp32 = (const unsigned int*)(gp + r0 * WW);
    for (int i2 = 0; i2 < 8; ++i2) {
        int idx = i2 * 256 + t;
        int row = idx >> 7;
        int c2  = idx & 127;
        unsigned int v = gp32[row * 128 + c2];
        int v0 = (int)(v & 0xFFFFu);
        int v1 = (int)(v >> 16);
        tile[row][2 * c2]     = (v0 == 0xFFFF) ? BIG : v0;
        tile[row][2 * c2 + 1] = (v1 == 0xFFFF) ? BIG : v1;
    }
    __syncthreads();

    double lsum = 0.0;
    for (int i = 0; i < ROWS_PER_BLK; ++i) {
        int best = tile[i][t];
        float xv = xp[(r0 + i) * WW + t];        // unconditional, coalesced
        #pragma unroll 1
        for (int bs = 1; bs < WW; bs += 4) {
            if (bs * bs >= best) break;          // lossless prune
            int m = best;
            #pragma unroll
            for (int u = 0; u < 4; ++u) {
                int r  = bs + u;
                int rr = r * r;
                int jl = max(t - r, 0);
                int jr = min(t + r, WW - 1);
                m = min(m, tile[i][jl] + rr);
                m = min(m, tile[i][jr] + rr);
            }
            best = m;
        }
        // best==0: feature px (term 0). best>=BIG: class absent (has_pos).
        if (best > 0 && best < BIG) {
            float dd   = sqrtf((float)best);           // exact-int sqrt
            float term = which ? (1.0f - dd) : dd;     // == -(d-1) exactly
            lsum += (double)(xv * term);
        }
    }

    // block reduction: wave butterfly then 4 wave leaders
    for (int off = 32; off > 0; off >>= 1)
        lsum += __shfl_down(lsum, off, 64);
    int lane = t & 63, wv = t >> 6;
    if (lane == 0) wsum[wv] = lsum;
    __syncthreads();

    if (t == 0) {
        double s = wsum[0] + wsum[1] + wsum[2] + wsum[3];
        atomicAdd(&acc[(bid & (NSTRIPE - 1)) * 8], s);   // device-scope f64
        asm volatile("s_waitcnt vmcnt(0)" ::: "memory"); // ack before ticket
        unsigned int ticket = atomicAdd(cnt, 1u);
        lastFlag = (ticket == NBLK2 - 1) ? 1 : 0;
    }
    __syncthreads();

    // last block: atomic reads serialize with all stripe RMWs -> exact total
    if (lastFlag && t < 64) {
        double v = atomicAdd(&acc[t * 8], 0.0);
        for (int off = 32; off > 0; off >>= 1)
            v += __shfl_down(v, off, 64);
        if (t == 0) out[0] = (float)(v * (1.0 / 2097152.0));
    }
}

extern "C" void kernel_launch(void* const* d_in, const int* in_sizes, int n_in,
                              void* d_out, int out_size, void* d_ws, size_t ws_size,
                              hipStream_t stream) {
    const float* x = (const float*)d_in[0];
    const int*   y = (const int*)d_in[1];
    float* out = (float*)d_out;

    // ws layout: [0, 8MB) u16 g planes; then 512 f64 (64 stripes, stride 8);
    // then u32 ticket counter.
    unsigned short* g   = (unsigned short*)d_ws;
    double*         acc = (double*)((char*)d_ws + (size_t)NPM * NPIX * sizeof(unsigned short));
    unsigned int*   cnt = (unsigned int*)((char*)acc + 512 * sizeof(double));

    edt_vpass<<<512,  256, 0, stream>>>(y, g, acc, cnt);
    edt_hpass<<<NBLK2, 256, 0, stream>>>(g, x, acc, cnt, out);
}